// Round 3
// baseline (1148.038 us; speedup 1.0000x reference)
//
#include <hip/hip_runtime.h>

typedef __attribute__((ext_vector_type(8))) short short8;
typedef __attribute__((ext_vector_type(4))) float floatx4;

#define NSEG 256      // binning grid (blocks); each owns a private output segment
#define NPB  256      // nodes per bucket
#define EPB_CAP 12800 // max edges per binning block staged in LDS (E/NSEG = 12500)
#define AGG_CAP 10240 // max edges per bucket staged in LDS (avg 8184, +22 sigma safe)

// f32 -> bf16 round-to-nearest-even
__device__ __forceinline__ short f2bf(float f) {
    unsigned int u = __float_as_uint(f);
    u = (u + 0x7FFFu + ((u >> 16) & 1u)) >> 16;
    return (short)u;
}

// ---------------- binning: block-segmented counting sort by dst>>8 ----------------
// Each block sorts its private edge slice in LDS, drains linearly (coalesced, no
// cross-XCD partial lines), and writes its per-bucket offset table (392 entries).
__global__ __launch_bounds__(256) void bin_edges(const int* __restrict__ eidx,
                                                 int* __restrict__ binned,
                                                 int* __restrict__ segoff,
                                                 int E, int epb) {
    __shared__ int ecnt[512];
    __shared__ int eoff[512];
    __shared__ int stage[EPB_CAP];
    __shared__ int wsum[4];
    int tid = threadIdx.x;
    int base = blockIdx.x * epb;
    int myE = E - base; if (myE > epb) myE = epb; if (myE < 0) myE = 0;

    ecnt[tid] = 0; ecnt[tid + 256] = 0;
    __syncthreads();
    for (int i = tid; i < myE; i += 256) {
        int d = eidx[E + base + i];
        atomicAdd(&ecnt[d >> 8], 1);
    }
    __syncthreads();
    // exclusive scan of 512 counts: 2 per thread + wave scan + wave-base fixup
    int c0 = ecnt[2 * tid], c1 = ecnt[2 * tid + 1];
    int p = c0 + c1;
    int v = p;
    int lane = tid & 63;
#pragma unroll
    for (int dlt = 1; dlt < 64; dlt <<= 1) {
        int t = __shfl_up(v, dlt, 64);
        if (lane >= dlt) v += t;
    }
    if (lane == 63) wsum[tid >> 6] = v;
    __syncthreads();
    int wb = 0;
    for (int wv = 0; wv < (tid >> 6); ++wv) wb += wsum[wv];
    int excl = wb + v - p;
    eoff[2 * tid] = excl;
    eoff[2 * tid + 1] = excl + c0;
    __syncthreads();
    // cursors (reuse ecnt)
    ecnt[2 * tid] = eoff[2 * tid];
    ecnt[2 * tid + 1] = eoff[2 * tid + 1];
    __syncthreads();
    for (int i = tid; i < myE; i += 256) {
        int s = eidx[base + i];
        int d = eidx[E + base + i];
        int b = d >> 8;
        int pos = atomicAdd(&ecnt[b], 1);
        stage[pos] = (s << 8) | (d & 255);   // src:17+ bits | dstlow:8
    }
    __syncthreads();
    for (int i = tid; i < myE; i += 256) binned[base + i] = stage[i];  // coalesced drain
    for (int j = tid; j < 392; j += 256) segoff[blockIdx.x * 392 + j] = base + eoff[j];
}

// ---------------- degree + dinv from binned edges (LDS counters) ----------------
__global__ __launch_bounds__(256) void deg_dinv(const int* __restrict__ binned,
                                                const int* __restrict__ segoff,
                                                float* __restrict__ dinv, int N) {
    __shared__ int s0[NSEG], s1[NSEG];
    __shared__ int cnt[NPB];
    int b = blockIdx.x, tid = threadIdx.x;
    s0[tid] = segoff[tid * 392 + b];
    s1[tid] = segoff[tid * 392 + b + 1];
    cnt[tid] = 0;
    __syncthreads();
    int g = tid >> 5, l = tid & 31;   // 8 groups of 32, independent segments
    for (int s = g; s < NSEG; s += 8) {
        int a = s0[s], e = s1[s];
        for (int j = a + l; j < e; j += 32) {
            int w = binned[j];
            atomicAdd(&cnt[w & 255], 1);
        }
    }
    __syncthreads();
    int n = b * NPB + tid;
    if (n < N) dinv[n] = rsqrtf((float)(cnt[tid] + 1));   // +1 self-loop
}

// ---------------- layer 1 GEMM: h1'[n] = dinv[n] * (x[n,:512] @ W1[:,16]) ----------------
__global__ __launch_bounds__(256) void gemm1_mfma(const float* __restrict__ x,
                                                  const float* __restrict__ w1,
                                                  const float* __restrict__ dinv,
                                                  float* __restrict__ h1,
                                                  int ntiles, int N) {
    __shared__ __align__(16) float wl[512 * 16];    // 32 KB
    int tid = threadIdx.x;
    for (int i = tid; i < 2048; i += 256)
        ((float4*)wl)[i] = ((const float4*)w1)[i];
    __syncthreads();

    int lane = tid & 63;
    int q = lane >> 4, r = lane & 15;

    short8 bf[16];
#pragma unroll
    for (int kk = 0; kk < 16; ++kk) {
        int kb = kk * 32 + q * 8;
        short8 t;
#pragma unroll
        for (int j = 0; j < 8; ++j) t[j] = f2bf(wl[(kb + j) * 16 + r]);
        bf[kk] = t;
    }

    int tile = blockIdx.x * 4 + (tid >> 6);
    if (tile >= ntiles) return;
    int nb = tile * 16;
    int row = nb + r; if (row >= N) row = N - 1;
    const float* xp = x + (size_t)row * 512 + q * 8;
    floatx4 acc = {0.f, 0.f, 0.f, 0.f};
#pragma unroll
    for (int kk = 0; kk < 16; ++kk) {
        float4 a0 = *(const float4*)(xp + kk * 32);
        float4 a1 = *(const float4*)(xp + kk * 32 + 4);
        short8 af;
        af[0] = f2bf(a0.x); af[1] = f2bf(a0.y); af[2] = f2bf(a0.z); af[3] = f2bf(a0.w);
        af[4] = f2bf(a1.x); af[5] = f2bf(a1.y); af[6] = f2bf(a1.z); af[7] = f2bf(a1.w);
        acc = __builtin_amdgcn_mfma_f32_16x16x32_bf16(af, bf[kk], acc, 0, 0, 0);
    }
#pragma unroll
    for (int i = 0; i < 4; ++i) {
        int rr = nb + q * 4 + i;
        if (rr < N) h1[(size_t)rr * 16 + r] = dinv[rr] * acc[i];
    }
}

// ---------------- bucket aggregation ----------------
// out[n] = dinv[n]*(sum_{src in N(n)} hp[src] + hp[n])   [pre-scaled inputs]
// relu_mode=1: out = dinv[n]*max(out+bias,0)  (layer-1 epilogue, pre-scales next layer)
__global__ __launch_bounds__(256) void agg_bucket(const float* __restrict__ hp,
                                                  const int* __restrict__ binned,
                                                  const int* __restrict__ segoff,
                                                  const float* __restrict__ dinv,
                                                  const float* __restrict__ bias,
                                                  float* __restrict__ outp,
                                                  int N, int relu_mode) {
    __shared__ int s0[NSEG], s1[NSEG], sdst[NSEG];
    __shared__ int eb[AGG_CAP];
    __shared__ float lout[NPB * 17];
    __shared__ int wsum2[4];
    int b = blockIdx.x, tid = threadIdx.x;
    s0[tid] = segoff[tid * 392 + b];
    s1[tid] = segoff[tid * 392 + b + 1];
    for (int i = tid; i < NPB * 17; i += 256) lout[i] = 0.f;
    __syncthreads();
    // prefix-scan segment lengths -> LDS dest offsets
    int len = s1[tid] - s0[tid];
    int v = len;
    int lane = tid & 63;
#pragma unroll
    for (int dlt = 1; dlt < 64; dlt <<= 1) {
        int t = __shfl_up(v, dlt, 64);
        if (lane >= dlt) v += t;
    }
    if (lane == 63) wsum2[tid >> 6] = v;
    __syncthreads();
    int wb = 0;
    for (int wv = 0; wv < (tid >> 6); ++wv) wb += wsum2[wv];
    sdst[tid] = wb + v - len;
    int total = wsum2[0] + wsum2[1] + wsum2[2] + wsum2[3];
    __syncthreads();
    // copy this bucket's edges into LDS (coalesced-ish per segment)
    int g = tid >> 5, l = tid & 31;
    for (int s = g; s < NSEG; s += 8) {
        int a = s0[s], e = s1[s], d0 = sdst[s];
        for (int j = l; j < e - a; j += 32) {
            int di = d0 + j;
            if (di < AGG_CAP) eb[di] = binned[a + j];
        }
    }
    __syncthreads();
    int cb = total < AGG_CAP ? total : AGG_CAP;
    // main loop: 16-lane groups, one edge each: gather 64B row, LDS-atomic accumulate
    int grp = tid >> 4, h = tid & 15;
    for (int i = grp; i < cb; i += 16) {
        int w = eb[i];
        float val = hp[(size_t)(w >> 8) * 16 + h];
        atomicAdd(&lout[(w & 255) * 17 + h], val);
    }
    // overflow fallback (statistically never for uniform dst)
    if (total > AGG_CAP) {
        for (int s = 0; s < NSEG; ++s) {
            int a = s0[s], d0 = sdst[s], lenS = s1[s] - a;
            int start = AGG_CAP - d0; if (start < 0) start = 0;
            if (start >= lenS) continue;
            for (int j = start + grp; j < lenS; j += 16) {
                int w = binned[a + j];
                float val = hp[(size_t)(w >> 8) * 16 + h];
                atomicAdd(&lout[(w & 255) * 17 + h], val);
            }
        }
    }
    __syncthreads();
    // epilogue
    for (int t = tid; t < NPB * 16; t += 256) {
        int j = t >> 4, hh = t & 15;
        int n = b * NPB + j;
        if (n >= N) continue;
        float dn = dinv[n];
        float o = dn * (lout[j * 17 + hh] + hp[(size_t)n * 16 + hh]);
        if (relu_mode) o = fmaxf(o + bias[hh], 0.f) * dn;
        outp[(size_t)n * 16 + hh] = o;
    }
}

// ---------------- fused W2 + bias + log_softmax ----------------
__global__ __launch_bounds__(256) void out_ls(const float* __restrict__ a2,
                                              const float* __restrict__ w2,
                                              const float* __restrict__ b2,
                                              float* __restrict__ out, int N) {
    __shared__ float w2s[704];
    __shared__ float b2s[40];
    int tid = threadIdx.x;
    for (int i = tid; i < 704; i += 256) w2s[i] = (i < 640) ? w2[i] : 0.0f;
    if (tid < 40) b2s[tid] = b2[tid];
    __syncthreads();
    int lane = tid & 63;
    int n = blockIdx.x * 4 + (tid >> 6);
    if (n >= N) return;
    const float* ar = a2 + (size_t)n * 16;
    bool act = lane < 40;
    float acc = act ? b2s[lane] : 0.0f;
#pragma unroll
    for (int k = 0; k < 16; ++k) {
        float av = ar[k];
        acc += av * w2s[k * 40 + lane];
    }
    float v = act ? acc : -__builtin_inff();
#pragma unroll
    for (int s = 32; s > 0; s >>= 1) v = fmaxf(v, __shfl_xor(v, s, 64));
    float ex = act ? expf(acc - v) : 0.0f;
    float ssum = ex;
#pragma unroll
    for (int s = 32; s > 0; s >>= 1) ssum += __shfl_xor(ssum, s, 64);
    float lse = logf(ssum);
    if (act) out[(size_t)n * 40 + lane] = acc - v - lse;
}

// ---------------- launch ----------------

extern "C" void kernel_launch(void* const* d_in, const int* in_sizes, int n_in,
                              void* d_out, int out_size, void* d_ws, size_t ws_size,
                              hipStream_t stream) {
    const float* x   = (const float*)d_in[0];
    const float* W1  = (const float*)d_in[1];
    const float* b1  = (const float*)d_in[2];
    const float* W2  = (const float*)d_in[3];
    const float* b2  = (const float*)d_in[4];
    const int*   eidx = (const int*)d_in[5];
    float* out = (float*)d_out;

    const int N = in_sizes[0] / 512;
    const int E = in_sizes[5] / 2;
    const int NB = (N + NPB - 1) / NPB;         // 391 buckets
    const int epb = (E + NSEG - 1) / NSEG;      // 12500

    char* w = (char*)d_ws;
    auto alloc = [&](size_t bytes) { char* p = w; w += (bytes + 255) & ~(size_t)255; return p; };
    int*   binned = (int*)alloc((size_t)E * 4);
    int*   segoff = (int*)alloc((size_t)NSEG * 392 * 4);
    float* dinv   = (float*)alloc((size_t)N * 4);
    float* h1     = (float*)alloc((size_t)N * 16 * 4);
    float* r1     = (float*)alloc((size_t)N * 16 * 4);
    float* a2     = h1;   // h1 dead after first agg

    bin_edges<<<NSEG, 256, 0, stream>>>(eidx, binned, segoff, E, epb);
    deg_dinv<<<NB, 256, 0, stream>>>(binned, segoff, dinv, N);

    int ntiles = (N + 15) / 16;
    gemm1_mfma<<<(ntiles + 3) / 4, 256, 0, stream>>>(x, W1, dinv, h1, ntiles, N);

    agg_bucket<<<NB, 256, 0, stream>>>(h1, binned, segoff, dinv, b1, r1, N, 1);
    agg_bucket<<<NB, 256, 0, stream>>>(r1, binned, segoff, dinv, (const float*)nullptr, a2, N, 0);

    out_ls<<<(N + 3) / 4, 256, 0, stream>>>(a2, W2, b2, out, N);
}

// Round 4
// 1089.472 us; speedup vs baseline: 1.0538x; 1.0538x over previous
//
#include <hip/hip_runtime.h>

typedef __attribute__((ext_vector_type(8))) short short8;
typedef __attribute__((ext_vector_type(4))) float floatx4;

#define NSEG 256      // binning blocks / segments per bucket
#define NPB  256      // nodes per bucket
#define EPB_CAP 12800 // edges staged per binning block (E/NSEG = 12500)
#define SPLIT 2       // agg blocks per bucket
#define SEGPB (NSEG / SPLIT)

// f32 -> bf16 round-to-nearest-even
__device__ __forceinline__ unsigned short f2bfu(float f) {
    unsigned int u = __float_as_uint(f);
    u = (u + 0x7FFFu + ((u >> 16) & 1u)) >> 16;
    return (unsigned short)u;
}

// ---------------- binning: block-segmented counting sort by dst>>8 ----------------
__global__ __launch_bounds__(256) void bin_edges(const int* __restrict__ eidx,
                                                 int* __restrict__ binned,
                                                 int* __restrict__ segoff,
                                                 int E, int epb) {
    __shared__ int ecnt[512];
    __shared__ int eoff[512];
    __shared__ int stage[EPB_CAP];
    __shared__ int wsum[4];
    int tid = threadIdx.x;
    int base = blockIdx.x * epb;
    int myE = E - base; if (myE > epb) myE = epb; if (myE < 0) myE = 0;

    ecnt[tid] = 0; ecnt[tid + 256] = 0;
    __syncthreads();
    for (int i = tid; i < myE; i += 256) {
        int d = eidx[E + base + i];
        atomicAdd(&ecnt[d >> 8], 1);
    }
    __syncthreads();
    int c0 = ecnt[2 * tid], c1 = ecnt[2 * tid + 1];
    int p = c0 + c1;
    int v = p;
    int lane = tid & 63;
#pragma unroll
    for (int dlt = 1; dlt < 64; dlt <<= 1) {
        int t = __shfl_up(v, dlt, 64);
        if (lane >= dlt) v += t;
    }
    if (lane == 63) wsum[tid >> 6] = v;
    __syncthreads();
    int wb = 0;
    for (int wv = 0; wv < (tid >> 6); ++wv) wb += wsum[wv];
    int excl = wb + v - p;
    eoff[2 * tid] = excl;
    eoff[2 * tid + 1] = excl + c0;
    __syncthreads();
    ecnt[2 * tid] = eoff[2 * tid];
    ecnt[2 * tid + 1] = eoff[2 * tid + 1];
    __syncthreads();
    for (int i = tid; i < myE; i += 256) {
        int s = eidx[base + i];
        int d = eidx[E + base + i];
        int b = d >> 8;
        int pos = atomicAdd(&ecnt[b], 1);
        stage[pos] = (s << 8) | (d & 255);   // src | dst-low-8
    }
    __syncthreads();
    for (int i = tid; i < myE; i += 256) binned[base + i] = stage[i];  // coalesced drain
    for (int j = tid; j < 392; j += 256) segoff[blockIdx.x * 392 + j] = base + eoff[j];
}

// ---------------- degree + dinv ----------------
__global__ __launch_bounds__(256) void deg_dinv(const int* __restrict__ binned,
                                                const int* __restrict__ segoff,
                                                float* __restrict__ dinv, int N) {
    __shared__ int s0[NSEG], s1[NSEG];
    __shared__ int cnt[NPB];
    int b = blockIdx.x, tid = threadIdx.x;
    s0[tid] = segoff[tid * 392 + b];
    s1[tid] = segoff[tid * 392 + b + 1];
    cnt[tid] = 0;
    __syncthreads();
    int g = tid >> 5, l = tid & 31;
    for (int s = g; s < NSEG; s += 8) {
        int a = s0[s], e = s1[s];
        for (int j = a + l; j < e; j += 32) {
            int w = binned[j];
            atomicAdd(&cnt[w & 255], 1);
        }
    }
    __syncthreads();
    int n = b * NPB + tid;
    if (n < N) dinv[n] = rsqrtf((float)(cnt[tid] + 1));
}

// ---------------- layer 1 GEMM: h16[n] = bf16( dinv[n] * (x[n] @ W1) ) ----------------
__global__ __launch_bounds__(256) void gemm1_mfma(const float* __restrict__ x,
                                                  const float* __restrict__ w1,
                                                  const float* __restrict__ dinv,
                                                  unsigned int* __restrict__ h16,
                                                  int ntiles, int N) {
    __shared__ __align__(16) float wl[512 * 16];
    int tid = threadIdx.x;
    for (int i = tid; i < 2048; i += 256)
        ((float4*)wl)[i] = ((const float4*)w1)[i];
    __syncthreads();

    int lane = tid & 63;
    int q = lane >> 4, r = lane & 15;

    short8 bf[16];
#pragma unroll
    for (int kk = 0; kk < 16; ++kk) {
        int kb = kk * 32 + q * 8;
        short8 t;
#pragma unroll
        for (int j = 0; j < 8; ++j) t[j] = (short)f2bfu(wl[(kb + j) * 16 + r]);
        bf[kk] = t;
    }

    int tile = blockIdx.x * 4 + (tid >> 6);
    if (tile >= ntiles) return;
    int nb = tile * 16;
    int row = nb + r; if (row >= N) row = N - 1;
    const float* xp = x + (size_t)row * 512 + q * 8;
    floatx4 acc = {0.f, 0.f, 0.f, 0.f};
#pragma unroll
    for (int kk = 0; kk < 16; ++kk) {
        float4 a0 = *(const float4*)(xp + kk * 32);
        float4 a1 = *(const float4*)(xp + kk * 32 + 4);
        short8 af;
        af[0] = (short)f2bfu(a0.x); af[1] = (short)f2bfu(a0.y);
        af[2] = (short)f2bfu(a0.z); af[3] = (short)f2bfu(a0.w);
        af[4] = (short)f2bfu(a1.x); af[5] = (short)f2bfu(a1.y);
        af[6] = (short)f2bfu(a1.z); af[7] = (short)f2bfu(a1.w);
        acc = __builtin_amdgcn_mfma_f32_16x16x32_bf16(af, bf[kk], acc, 0, 0, 0);
    }
    // C/D: col=r (feature), row=q*4+i. Pair feats (r, r^1) via shfl, even lane packs uint.
#pragma unroll
    for (int i = 0; i < 4; ++i) {
        int rr = nb + q * 4 + i;
        int rrc = rr < N ? rr : N - 1;
        float v = dinv[rrc] * acc[i];
        float o = __shfl_xor(v, 1, 64);
        if (((r & 1) == 0) && rr < N) {
            unsigned int pk = (unsigned int)f2bfu(v) | ((unsigned int)f2bfu(o) << 16);
            h16[(size_t)rr * 8 + (r >> 1)] = pk;
        }
    }
}

// ---------------- bucket aggregation (partial): part[b] += sum of hp16[src] ----------------
// Grid (NB, SPLIT). 8 lanes per edge, unroll-4 for MLP. No edge staging; ~18.5 KB LDS.
__global__ __launch_bounds__(256) void agg_bucket(const unsigned int* __restrict__ hp16,
                                                  const int* __restrict__ binned,
                                                  const int* __restrict__ segoff,
                                                  float* __restrict__ part,
                                                  int partstride) {
    __shared__ int s0[SEGPB], s1[SEGPB];
    __shared__ float lout[NPB * 17];
    int b = blockIdx.x, half = blockIdx.y, tid = threadIdx.x;
    if (tid < SEGPB) {
        int s = half * SEGPB + tid;
        s0[tid] = segoff[s * 392 + b];
        s1[tid] = segoff[s * 392 + b + 1];
    }
    for (int i = tid; i < NPB * 17; i += 256) lout[i] = 0.f;
    __syncthreads();
    int grp = tid >> 3, l = tid & 7;
    for (int s = grp; s < SEGPB; s += 32) {
        int j = s0[s], e = s1[s];
        for (; j + 4 <= e; j += 4) {
            int w0 = binned[j], w1 = binned[j + 1], w2 = binned[j + 2], w3 = binned[j + 3];
            unsigned int g0 = hp16[(size_t)(w0 >> 8) * 8 + l];
            unsigned int g1 = hp16[(size_t)(w1 >> 8) * 8 + l];
            unsigned int g2 = hp16[(size_t)(w2 >> 8) * 8 + l];
            unsigned int g3 = hp16[(size_t)(w3 >> 8) * 8 + l];
            float* r0 = &lout[(w0 & 255) * 17 + 2 * l];
            float* r1 = &lout[(w1 & 255) * 17 + 2 * l];
            float* r2 = &lout[(w2 & 255) * 17 + 2 * l];
            float* r3 = &lout[(w3 & 255) * 17 + 2 * l];
            atomicAdd(r0,     __uint_as_float(g0 << 16));
            atomicAdd(r0 + 1, __uint_as_float(g0 & 0xffff0000u));
            atomicAdd(r1,     __uint_as_float(g1 << 16));
            atomicAdd(r1 + 1, __uint_as_float(g1 & 0xffff0000u));
            atomicAdd(r2,     __uint_as_float(g2 << 16));
            atomicAdd(r2 + 1, __uint_as_float(g2 & 0xffff0000u));
            atomicAdd(r3,     __uint_as_float(g3 << 16));
            atomicAdd(r3 + 1, __uint_as_float(g3 & 0xffff0000u));
        }
        for (; j < e; ++j) {
            int w = binned[j];
            unsigned int g = hp16[(size_t)(w >> 8) * 8 + l];
            float* rr = &lout[(w & 255) * 17 + 2 * l];
            atomicAdd(rr,     __uint_as_float(g << 16));
            atomicAdd(rr + 1, __uint_as_float(g & 0xffff0000u));
        }
    }
    __syncthreads();
    float* dst = part + (size_t)half * partstride + (size_t)b * (NPB * 16);
    for (int i = tid; i < NPB * 16; i += 256)
        dst[i] = lout[(i >> 4) * 17 + (i & 15)];
}

// ---------------- merge partials + self-loop + scale (+bias/relu -> bf16 | plain -> f32) ----
__global__ __launch_bounds__(256) void agg_epilogue(const float* __restrict__ p0,
                                                    const float* __restrict__ p1,
                                                    const unsigned int* __restrict__ hp16,
                                                    const float* __restrict__ dinv,
                                                    const float* __restrict__ bias,
                                                    unsigned int* __restrict__ out16,
                                                    float* __restrict__ outf,
                                                    int N, int relu_mode) {
    int t = blockIdx.x * 256 + threadIdx.x;
    if (t >= N * 8) return;
    int n = t >> 3, l = t & 7;
    unsigned int s = hp16[t];
    float slo = __uint_as_float(s << 16);
    float shi = __uint_as_float(s & 0xffff0000u);
    size_t base = (size_t)n * 16 + 2 * l;
    float2 a = *(const float2*)(p0 + base);
    float2 c = *(const float2*)(p1 + base);
    float dn = dinv[n];
    float o0 = dn * (a.x + c.x + slo);
    float o1 = dn * (a.y + c.y + shi);
    if (relu_mode) {
        o0 = fmaxf(o0 + bias[2 * l], 0.f) * dn;
        o1 = fmaxf(o1 + bias[2 * l + 1], 0.f) * dn;
        out16[t] = (unsigned int)f2bfu(o0) | ((unsigned int)f2bfu(o1) << 16);
    } else {
        *(float2*)(outf + base) = make_float2(o0, o1);
    }
}

// ---------------- fused W2 + bias + log_softmax ----------------
__global__ __launch_bounds__(256) void out_ls(const float* __restrict__ a2,
                                              const float* __restrict__ w2,
                                              const float* __restrict__ b2,
                                              float* __restrict__ out, int N) {
    __shared__ float w2s[704];
    __shared__ float b2s[40];
    int tid = threadIdx.x;
    for (int i = tid; i < 704; i += 256) w2s[i] = (i < 640) ? w2[i] : 0.0f;
    if (tid < 40) b2s[tid] = b2[tid];
    __syncthreads();
    int lane = tid & 63;
    int n = blockIdx.x * 4 + (tid >> 6);
    if (n >= N) return;
    const float* ar = a2 + (size_t)n * 16;
    bool act = lane < 40;
    float acc = act ? b2s[lane] : 0.0f;
#pragma unroll
    for (int k = 0; k < 16; ++k) {
        float av = ar[k];
        acc += av * w2s[k * 40 + lane];
    }
    float v = act ? acc : -__builtin_inff();
#pragma unroll
    for (int s = 32; s > 0; s >>= 1) v = fmaxf(v, __shfl_xor(v, s, 64));
    float ex = act ? expf(acc - v) : 0.0f;
    float ssum = ex;
#pragma unroll
    for (int s = 32; s > 0; s >>= 1) ssum += __shfl_xor(ssum, s, 64);
    float lse = logf(ssum);
    if (act) out[(size_t)n * 40 + lane] = acc - v - lse;
}

// ---------------- launch ----------------

extern "C" void kernel_launch(void* const* d_in, const int* in_sizes, int n_in,
                              void* d_out, int out_size, void* d_ws, size_t ws_size,
                              hipStream_t stream) {
    const float* x   = (const float*)d_in[0];
    const float* W1  = (const float*)d_in[1];
    const float* b1  = (const float*)d_in[2];
    const float* W2  = (const float*)d_in[3];
    const float* b2  = (const float*)d_in[4];
    const int*   eidx = (const int*)d_in[5];
    float* out = (float*)d_out;

    const int N = in_sizes[0] / 512;
    const int E = in_sizes[5] / 2;
    const int NB = (N + NPB - 1) / NPB;       // 391 buckets
    const int epb = (E + NSEG - 1) / NSEG;    // 12500
    const int partstride = NB * NPB * 16;     // floats per partial buffer

    char* w = (char*)d_ws;
    auto alloc = [&](size_t bytes) { char* p = w; w += (bytes + 255) & ~(size_t)255; return p; };
    int*          binned = (int*)alloc((size_t)E * 4);
    int*          segoff = (int*)alloc((size_t)NSEG * 392 * 4);
    float*        dinv   = (float*)alloc((size_t)N * 4);
    unsigned int* h16    = (unsigned int*)alloc((size_t)N * 32);
    unsigned int* r16    = (unsigned int*)alloc((size_t)N * 32);
    float*        a2     = (float*)alloc((size_t)N * 16 * 4);
    float*        parts  = (float*)alloc((size_t)SPLIT * partstride * 4);

    bin_edges<<<NSEG, 256, 0, stream>>>(eidx, binned, segoff, E, epb);
    deg_dinv<<<NB, 256, 0, stream>>>(binned, segoff, dinv, N);

    int ntiles = (N + 15) / 16;
    gemm1_mfma<<<(ntiles + 3) / 4, 256, 0, stream>>>(x, W1, dinv, h16, ntiles, N);

    agg_bucket<<<dim3(NB, SPLIT), 256, 0, stream>>>(h16, binned, segoff, parts, partstride);
    agg_epilogue<<<(N * 8 + 255) / 256, 256, 0, stream>>>(parts, parts + partstride, h16, dinv,
                                                          b1, r16, (float*)nullptr, N, 1);

    agg_bucket<<<dim3(NB, SPLIT), 256, 0, stream>>>(r16, binned, segoff, parts, partstride);
    agg_epilogue<<<(N * 8 + 255) / 256, 256, 0, stream>>>(parts, parts + partstride, r16, dinv,
                                                          (const float*)nullptr, (unsigned int*)nullptr,
                                                          a2, N, 0);

    out_ls<<<(N + 3) / 4, 256, 0, stream>>>(a2, W2, b2, out, N);
}

// Round 5
// 1012.990 us; speedup vs baseline: 1.1333x; 1.0755x over previous
//
#include <hip/hip_runtime.h>

typedef __attribute__((ext_vector_type(8))) short short8;
typedef __attribute__((ext_vector_type(4))) float floatx4;

#define NSEG 256      // binning blocks / segments per bucket
#define NPB  256      // nodes per bucket
#define EPB_CAP 12800 // edges staged per binning block (E/NSEG = 12500)
#define SPLIT 4       // agg blocks per bucket
#define SEGPB (NSEG / SPLIT)

// f32 -> bf16 round-to-nearest-even
__device__ __forceinline__ unsigned short f2bfu(float f) {
    unsigned int u = __float_as_uint(f);
    u = (u + 0x7FFFu + ((u >> 16) & 1u)) >> 16;
    return (unsigned short)u;
}

// ---------------- binning: block-segmented counting sort by dst>>8 ----------------
__global__ __launch_bounds__(256) void bin_edges(const int* __restrict__ eidx,
                                                 int* __restrict__ binned,
                                                 int* __restrict__ segoff,
                                                 int E, int epb) {
    __shared__ int ecnt[512];
    __shared__ int eoff[512];
    __shared__ int stage[EPB_CAP];
    __shared__ int wsum[4];
    int tid = threadIdx.x;
    int base = blockIdx.x * epb;
    int myE = E - base; if (myE > epb) myE = epb; if (myE < 0) myE = 0;

    ecnt[tid] = 0; ecnt[tid + 256] = 0;
    __syncthreads();
    for (int i = tid; i < myE; i += 256) {
        int d = eidx[E + base + i];
        atomicAdd(&ecnt[d >> 8], 1);
    }
    __syncthreads();
    int c0 = ecnt[2 * tid], c1 = ecnt[2 * tid + 1];
    int p = c0 + c1;
    int v = p;
    int lane = tid & 63;
#pragma unroll
    for (int dlt = 1; dlt < 64; dlt <<= 1) {
        int t = __shfl_up(v, dlt, 64);
        if (lane >= dlt) v += t;
    }
    if (lane == 63) wsum[tid >> 6] = v;
    __syncthreads();
    int wb = 0;
    for (int wv = 0; wv < (tid >> 6); ++wv) wb += wsum[wv];
    int excl = wb + v - p;
    eoff[2 * tid] = excl;
    eoff[2 * tid + 1] = excl + c0;
    __syncthreads();
    ecnt[2 * tid] = eoff[2 * tid];
    ecnt[2 * tid + 1] = eoff[2 * tid + 1];
    __syncthreads();
    for (int i = tid; i < myE; i += 256) {
        int s = eidx[base + i];
        int d = eidx[E + base + i];
        int b = d >> 8;
        int pos = atomicAdd(&ecnt[b], 1);
        stage[pos] = (s << 8) | (d & 255);   // src | dst-low-8
    }
    __syncthreads();
    for (int i = tid; i < myE; i += 256) binned[base + i] = stage[i];  // coalesced drain
    for (int j = tid; j < 392; j += 256) segoff[blockIdx.x * 392 + j] = base + eoff[j];
}

// ---------------- degree partials: LDS counts per sub-block, one global add per node ----------
__global__ __launch_bounds__(256) void deg_part(const int* __restrict__ binned,
                                                const int* __restrict__ segoff,
                                                int* __restrict__ gcnt) {
    __shared__ int s0[SEGPB], s1[SEGPB];
    __shared__ int cnt[NPB];
    int b = blockIdx.x, half = blockIdx.y, tid = threadIdx.x;
    if (tid < SEGPB) {
        int s = half * SEGPB + tid;
        s0[tid] = segoff[s * 392 + b];
        s1[tid] = segoff[s * 392 + b + 1];
    }
    cnt[tid] = 0;
    __syncthreads();
    int g = tid >> 5, l = tid & 31;   // 8 groups of 32 lanes
    for (int s = g; s < SEGPB; s += 8) {
        int a = s0[s], e = s1[s];
        for (int j = a + l; j < e; j += 32) {
            int w = __builtin_nontemporal_load(&binned[j]);
            atomicAdd(&cnt[w & 255], 1);
        }
    }
    __syncthreads();
    int c = cnt[tid];
    if (c) atomicAdd(&gcnt[b * NPB + tid], c);
}

__global__ void dinv_k(const int* __restrict__ gcnt, float* __restrict__ dinv, int N) {
    int n = blockIdx.x * 256 + threadIdx.x;
    if (n < N) dinv[n] = rsqrtf((float)(gcnt[n] + 1));
}

__global__ void zero_i32(int* __restrict__ p, int n) {
    int i = blockIdx.x * blockDim.x + threadIdx.x;
    if (i < n) p[i] = 0;
}

// ---------------- layer 1 GEMM: h16[n] = bf16( dinv[n] * (x[n] @ W1) ) ----------------
__global__ __launch_bounds__(256) void gemm1_mfma(const float* __restrict__ x,
                                                  const float* __restrict__ w1,
                                                  const float* __restrict__ dinv,
                                                  unsigned int* __restrict__ h16,
                                                  int ntiles, int N) {
    __shared__ __align__(16) float wl[512 * 16];
    int tid = threadIdx.x;
    for (int i = tid; i < 2048; i += 256)
        ((float4*)wl)[i] = ((const float4*)w1)[i];
    __syncthreads();

    int lane = tid & 63;
    int q = lane >> 4, r = lane & 15;

    short8 bf[16];
#pragma unroll
    for (int kk = 0; kk < 16; ++kk) {
        int kb = kk * 32 + q * 8;
        short8 t;
#pragma unroll
        for (int j = 0; j < 8; ++j) t[j] = (short)f2bfu(wl[(kb + j) * 16 + r]);
        bf[kk] = t;
    }

    int tile = blockIdx.x * 4 + (tid >> 6);
    if (tile >= ntiles) return;
    int nb = tile * 16;
    int row = nb + r; if (row >= N) row = N - 1;
    const float* xp = x + (size_t)row * 512 + q * 8;
    floatx4 acc = {0.f, 0.f, 0.f, 0.f};
#pragma unroll
    for (int kk = 0; kk < 16; ++kk) {
        float4 a0 = *(const float4*)(xp + kk * 32);
        float4 a1 = *(const float4*)(xp + kk * 32 + 4);
        short8 af;
        af[0] = (short)f2bfu(a0.x); af[1] = (short)f2bfu(a0.y);
        af[2] = (short)f2bfu(a0.z); af[3] = (short)f2bfu(a0.w);
        af[4] = (short)f2bfu(a1.x); af[5] = (short)f2bfu(a1.y);
        af[6] = (short)f2bfu(a1.z); af[7] = (short)f2bfu(a1.w);
        acc = __builtin_amdgcn_mfma_f32_16x16x32_bf16(af, bf[kk], acc, 0, 0, 0);
    }
#pragma unroll
    for (int i = 0; i < 4; ++i) {
        int rr = nb + q * 4 + i;
        int rrc = rr < N ? rr : N - 1;
        float v = dinv[rrc] * acc[i];
        float o = __shfl_xor(v, 1, 64);
        if (((r & 1) == 0) && rr < N) {
            unsigned int pk = (unsigned int)f2bfu(v) | ((unsigned int)f2bfu(o) << 16);
            h16[(size_t)rr * 8 + (r >> 1)] = pk;
        }
    }
}

// ---------------- bucket aggregation (partial sums) ----------------
// Grid (NB, SPLIT). 8 lanes/edge, unroll-8 MLP, non-temporal edge stream.
__global__ __launch_bounds__(256) void agg_bucket(const unsigned int* __restrict__ hp16,
                                                  const int* __restrict__ binned,
                                                  const int* __restrict__ segoff,
                                                  float* __restrict__ part,
                                                  int partstride) {
    __shared__ int s0[SEGPB], s1[SEGPB];
    __shared__ float lout[NPB * 17];
    int b = blockIdx.x, half = blockIdx.y, tid = threadIdx.x;
    if (tid < SEGPB) {
        int s = half * SEGPB + tid;
        s0[tid] = segoff[s * 392 + b];
        s1[tid] = segoff[s * 392 + b + 1];
    }
    for (int i = tid; i < NPB * 17; i += 256) lout[i] = 0.f;
    __syncthreads();
    int grp = tid >> 3, l = tid & 7;
    for (int s = grp; s < SEGPB; s += 32) {
        int j = s0[s], e = s1[s];
        for (; j + 8 <= e; j += 8) {
            int w[8];
#pragma unroll
            for (int k = 0; k < 8; ++k) w[k] = __builtin_nontemporal_load(&binned[j + k]);
            unsigned int g[8];
#pragma unroll
            for (int k = 0; k < 8; ++k) g[k] = hp16[(size_t)(w[k] >> 8) * 8 + l];
#pragma unroll
            for (int k = 0; k < 8; ++k) {
                float* r = &lout[(w[k] & 255) * 17 + 2 * l];
                atomicAdd(r,     __uint_as_float(g[k] << 16));
                atomicAdd(r + 1, __uint_as_float(g[k] & 0xffff0000u));
            }
        }
        for (; j < e; ++j) {
            int w = __builtin_nontemporal_load(&binned[j]);
            unsigned int g = hp16[(size_t)(w >> 8) * 8 + l];
            float* rr = &lout[(w & 255) * 17 + 2 * l];
            atomicAdd(rr,     __uint_as_float(g << 16));
            atomicAdd(rr + 1, __uint_as_float(g & 0xffff0000u));
        }
    }
    __syncthreads();
    float* dst = part + (size_t)half * partstride + (size_t)b * (NPB * 16);
    for (int i = tid; i < NPB * 16; i += 256)
        dst[i] = lout[(i >> 4) * 17 + (i & 15)];
}

// ---------------- merge partials + self-loop + scale (+bias/relu -> bf16 | plain -> f32) ----
__global__ __launch_bounds__(256) void agg_epilogue(const float* __restrict__ part,
                                                    int partstride,
                                                    const unsigned int* __restrict__ hp16,
                                                    const float* __restrict__ dinv,
                                                    const float* __restrict__ bias,
                                                    unsigned int* __restrict__ out16,
                                                    float* __restrict__ outf,
                                                    int N, int relu_mode) {
    int t = blockIdx.x * 256 + threadIdx.x;
    if (t >= N * 8) return;
    int n = t >> 3, l = t & 7;
    unsigned int s = hp16[t];
    float o0 = __uint_as_float(s << 16);
    float o1 = __uint_as_float(s & 0xffff0000u);
    size_t base = (size_t)n * 16 + 2 * l;
#pragma unroll
    for (int k = 0; k < SPLIT; ++k) {
        float2 a = *(const float2*)(part + (size_t)k * partstride + base);
        o0 += a.x; o1 += a.y;
    }
    float dn = dinv[n];
    o0 *= dn; o1 *= dn;
    if (relu_mode) {
        o0 = fmaxf(o0 + bias[2 * l], 0.f) * dn;
        o1 = fmaxf(o1 + bias[2 * l + 1], 0.f) * dn;
        out16[t] = (unsigned int)f2bfu(o0) | ((unsigned int)f2bfu(o1) << 16);
    } else {
        *(float2*)(outf + base) = make_float2(o0, o1);
    }
}

// ---------------- fused W2 + bias + log_softmax ----------------
__global__ __launch_bounds__(256) void out_ls(const float* __restrict__ a2,
                                              const float* __restrict__ w2,
                                              const float* __restrict__ b2,
                                              float* __restrict__ out, int N) {
    __shared__ float w2s[704];
    __shared__ float b2s[40];
    int tid = threadIdx.x;
    for (int i = tid; i < 704; i += 256) w2s[i] = (i < 640) ? w2[i] : 0.0f;
    if (tid < 40) b2s[tid] = b2[tid];
    __syncthreads();
    int lane = tid & 63;
    int n = blockIdx.x * 4 + (tid >> 6);
    if (n >= N) return;
    const float* ar = a2 + (size_t)n * 16;
    bool act = lane < 40;
    float acc = act ? b2s[lane] : 0.0f;
#pragma unroll
    for (int k = 0; k < 16; ++k) {
        float av = ar[k];
        acc += av * w2s[k * 40 + lane];
    }
    float v = act ? acc : -__builtin_inff();
#pragma unroll
    for (int s = 32; s > 0; s >>= 1) v = fmaxf(v, __shfl_xor(v, s, 64));
    float ex = act ? expf(acc - v) : 0.0f;
    float ssum = ex;
#pragma unroll
    for (int s = 32; s > 0; s >>= 1) ssum += __shfl_xor(ssum, s, 64);
    float lse = logf(ssum);
    if (act) out[(size_t)n * 40 + lane] = acc - v - lse;
}

// ---------------- launch ----------------

extern "C" void kernel_launch(void* const* d_in, const int* in_sizes, int n_in,
                              void* d_out, int out_size, void* d_ws, size_t ws_size,
                              hipStream_t stream) {
    const float* x   = (const float*)d_in[0];
    const float* W1  = (const float*)d_in[1];
    const float* b1  = (const float*)d_in[2];
    const float* W2  = (const float*)d_in[3];
    const float* b2  = (const float*)d_in[4];
    const int*   eidx = (const int*)d_in[5];
    float* out = (float*)d_out;

    const int N = in_sizes[0] / 512;
    const int E = in_sizes[5] / 2;
    const int NB = (N + NPB - 1) / NPB;       // 391 buckets
    const int epb = (E + NSEG - 1) / NSEG;    // 12500
    const int partstride = NB * NPB * 16;     // floats per partial buffer

    char* w = (char*)d_ws;
    auto alloc = [&](size_t bytes) { char* p = w; w += (bytes + 255) & ~(size_t)255; return p; };
    int*          binned = (int*)alloc((size_t)E * 4);
    int*          segoff = (int*)alloc((size_t)NSEG * 392 * 4);
    int*          gcnt   = (int*)alloc((size_t)NB * NPB * 4);
    float*        dinv   = (float*)alloc((size_t)N * 4);
    unsigned int* h16    = (unsigned int*)alloc((size_t)N * 32);
    unsigned int* r16    = (unsigned int*)alloc((size_t)N * 32);
    float*        a2     = (float*)alloc((size_t)N * 16 * 4);
    float*        parts  = (float*)alloc((size_t)SPLIT * partstride * 4);

    bin_edges<<<NSEG, 256, 0, stream>>>(eidx, binned, segoff, E, epb);
    zero_i32<<<(NB * NPB + 255) / 256, 256, 0, stream>>>(gcnt, NB * NPB);
    deg_part<<<dim3(NB, SPLIT), 256, 0, stream>>>(binned, segoff, gcnt);
    dinv_k<<<(N + 255) / 256, 256, 0, stream>>>(gcnt, dinv, N);

    int ntiles = (N + 15) / 16;
    gemm1_mfma<<<(ntiles + 3) / 4, 256, 0, stream>>>(x, W1, dinv, h16, ntiles, N);

    agg_bucket<<<dim3(NB, SPLIT), 256, 0, stream>>>(h16, binned, segoff, parts, partstride);
    agg_epilogue<<<(N * 8 + 255) / 256, 256, 0, stream>>>(parts, partstride, h16, dinv,
                                                          b1, r16, (float*)nullptr, N, 1);

    agg_bucket<<<dim3(NB, SPLIT), 256, 0, stream>>>(r16, binned, segoff, parts, partstride);
    agg_epilogue<<<(N * 8 + 255) / 256, 256, 0, stream>>>(parts, partstride, r16, dinv,
                                                          (const float*)nullptr, (unsigned int*)nullptr,
                                                          a2, N, 0);

    out_ls<<<(N + 3) / 4, 256, 0, stream>>>(a2, W2, b2, out, N);
}